// Round 8
// baseline (435.537 us; speedup 1.0000x reference)
//
#include <hip/hip_runtime.h>
#include <hip/hip_bf16.h>

// Hard-concrete constants
#define BETA_INV 1.51515151515f   // 1/0.66
#define ZMG      1.2f             // ZETA - GAMMA
#define GAMMA_C  (-0.1f)

#define NPB        64             // nodes per bucket
#define NPB_SHIFT  6
#define CAP        2048           // max edges per bucket (mean 1088, sigma 32)

// fp32 -> bf16 (round-to-nearest-even), as raw ushort bits
__device__ __forceinline__ ushort f32_to_bf16(float f) {
  unsigned u = __float_as_uint(f);
  u += 0x7fffu + ((u >> 16) & 1u);
  return (ushort)(u >> 16);
}

// ---------------------------------------------------------------------------
// Kernel 1: ft = x @ W + b (bf16 out), fused a1 = ft.attn_l, a2 = ft.attn_r
// 64 rows x 128 cols per block of 256 threads. x tile in LDS (33.8 KB,
// stride 132); W read from global (L2-resident, broadcast). Thread (tr,tc):
// tc in [0,32) -> 4 cols, tr in [0,8) -> 8 rows.
// ---------------------------------------------------------------------------
__global__ __launch_bounds__(256, 3) void gemm_ft(
    const float* __restrict__ x, const float* __restrict__ W,
    const float* __restrict__ bvec, const float* __restrict__ attn_l,
    const float* __restrict__ attn_r, ushort* __restrict__ ftb,
    float* __restrict__ a1, float* __restrict__ a2, int n) {
  __shared__ float xs[64 * 132];
  const int tid = threadIdx.x;

  const int row0 = blockIdx.x * 64;
  for (int i = tid; i < 2048; i += 256) {
    int r = i >> 5, c4 = i & 31;
    int gr = row0 + r;
    float4 v = make_float4(0.f, 0.f, 0.f, 0.f);
    if (gr < n) v = ((const float4*)(x + (size_t)gr * 128))[c4];
    *(float4*)(xs + r * 132 + c4 * 4) = v;
  }
  __syncthreads();

  const int tc = tid & 31;   // col group (4 cols)
  const int tr = tid >> 5;   // row group (8 rows)
  float4 bb = ((const float4*)bvec)[tc];
  float4 acc[8];
#pragma unroll
  for (int r = 0; r < 8; ++r) acc[r] = bb;

  for (int k4 = 0; k4 < 32; ++k4) {
    float4 w0 = ((const float4*)(W + (k4 * 4 + 0) * 128))[tc];
    float4 w1 = ((const float4*)(W + (k4 * 4 + 1) * 128))[tc];
    float4 w2 = ((const float4*)(W + (k4 * 4 + 2) * 128))[tc];
    float4 w3 = ((const float4*)(W + (k4 * 4 + 3) * 128))[tc];
#pragma unroll
    for (int r = 0; r < 8; ++r) {
      float4 xv = *(const float4*)(xs + (8 * tr + r) * 132 + k4 * 4);
      acc[r].x += xv.x * w0.x + xv.y * w1.x + xv.z * w2.x + xv.w * w3.x;
      acc[r].y += xv.x * w0.y + xv.y * w1.y + xv.z * w2.y + xv.w * w3.y;
      acc[r].z += xv.x * w0.z + xv.y * w1.z + xv.z * w2.z + xv.w * w3.z;
      acc[r].w += xv.x * w0.w + xv.y * w1.w + xv.z * w2.w + xv.w * w3.w;
    }
  }

  float4 al = ((const float4*)attn_l)[tc];
  float4 ar = ((const float4*)attn_r)[tc];
#pragma unroll
  for (int r = 0; r < 8; ++r) {
    int gr = row0 + 8 * tr + r;
    if (gr < n) {
      ushort4 h;
      h.x = f32_to_bf16(acc[r].x);
      h.y = f32_to_bf16(acc[r].y);
      h.z = f32_to_bf16(acc[r].z);
      h.w = f32_to_bf16(acc[r].w);
      *(ushort4*)(ftb + (size_t)gr * 128 + tc * 4) = h;
    }
    float s1 = acc[r].x * al.x + acc[r].y * al.y + acc[r].z * al.z +
               acc[r].w * al.w;
    float s2 = acc[r].x * ar.x + acc[r].y * ar.y + acc[r].z * ar.z +
               acc[r].w * ar.w;
#pragma unroll
    for (int off = 16; off; off >>= 1) {
      s1 += __shfl_xor(s1, off);
      s2 += __shfl_xor(s2, off);
    }
    if (tc == 0 && gr < n) {
      a1[gr] = s1;
      a2[gr] = s2;
    }
  }
}

// ---------------------------------------------------------------------------
// Kernel 2: bucket histogram (counters padded x4 ints to spread hot lines)
// ---------------------------------------------------------------------------
__global__ __launch_bounds__(256) void hist_bucket(const int* __restrict__ dst,
                                                   int* __restrict__ bcnt,
                                                   int E) {
  int e = blockIdx.x * blockDim.x + threadIdx.x;
  if (e < E) atomicAdd(&bcnt[(dst[e] >> NPB_SHIFT) * 4], 1);
}

// ---------------------------------------------------------------------------
// Kernel 3: single-block scan over NB buckets -> boff[NB+1], bfill=starts
// ---------------------------------------------------------------------------
__global__ __launch_bounds__(1024) void scan_buckets(
    const int* __restrict__ bcnt, int* __restrict__ boff,
    int* __restrict__ bfill, int NB) {
  __shared__ int sd[1024];
  __shared__ int carry_s;
  if (threadIdx.x == 0) carry_s = 0;
  int nchunk = (NB + 1023) / 1024;
  for (int c = 0; c < nchunk; ++c) {
    int i = c * 1024 + threadIdx.x;
    int v = (i < NB) ? bcnt[i * 4] : 0;
    __syncthreads();
    sd[threadIdx.x] = v;
    __syncthreads();
    for (int off = 1; off < 1024; off <<= 1) {
      int t = (threadIdx.x >= off) ? sd[threadIdx.x - off] : 0;
      __syncthreads();
      sd[threadIdx.x] += t;
      __syncthreads();
    }
    int carry = carry_s;
    if (i < NB) {
      int excl = carry + sd[threadIdx.x] - v;
      boff[i] = excl;
      bfill[i * 4] = excl;
    }
    __syncthreads();
    if (threadIdx.x == 1023) carry_s = carry + sd[1023];
  }
  __syncthreads();
  if (threadIdx.x == 0) boff[NB] = carry_s;
}

// ---------------------------------------------------------------------------
// Kernel 4: gate + scatter uint2{(dst_local<<26)|src, gate_bits} into the
// dst's bucket segment. Concurrent atomics on a bucket yield adjacent
// positions -> write lines merge (dense writes, not 64B/edge).
// ---------------------------------------------------------------------------
__global__ __launch_bounds__(256) void edge_gate_scatter(
    const int* __restrict__ src, const int* __restrict__ dst,
    const float* __restrict__ a1, const float* __restrict__ a2,
    const float* __restrict__ bias, int* __restrict__ bfill,
    uint2* __restrict__ pairs, int E) {
  int e = blockIdx.x * blockDim.x + threadIdx.x;
  if (e >= E) return;
  int s = src[e], d = dst[e];
  float val = 1.0f;
  if (s != d) {
    float logit = (a1[s] + a2[d] + bias[0]) * BETA_INV;
    float sg = 1.0f / (1.0f + __expf(-logit));
    val = fminf(fmaxf(sg * ZMG + GAMMA_C, 0.0f), 1.0f);
  }
  int bkt = d >> NPB_SHIFT;
  unsigned dl = (unsigned)(d & (NPB - 1));
  int pos = atomicAdd(&bfill[bkt * 4], 1);
  pairs[pos] = make_uint2((dl << 26) | (unsigned)s, __float_as_uint(val));
}

// ---------------------------------------------------------------------------
// Kernel 5: per-bucket aggregate. Block = one bucket: LDS counting-sort the
// bucket's edges by local dst, then wave-per-node gather+accumulate.
// ---------------------------------------------------------------------------
__global__ __launch_bounds__(256) void aggregate_bucket(
    const uint2* __restrict__ pairs, const int* __restrict__ boff,
    const ushort* __restrict__ ftb, float* __restrict__ out, int n) {
  __shared__ uint2 sorted[CAP];
  __shared__ int lstart[NPB + 1];
  __shared__ int lfill[NPB];
  const int tid = threadIdx.x;
  const int bkt = blockIdx.x;
  const int e0 = boff[bkt];
  const int cnt = min(boff[bkt + 1] - e0, CAP);

  if (tid < NPB) lfill[tid] = 0;
  __syncthreads();

  // load this bucket's edges into registers (static indexing), count per dl
  unsigned pw0[8], pw1[8];
  int pdl[8];
#pragma unroll
  for (int i = 0; i < 8; ++i) {
    int idx = tid + i * 256;
    pw0[i] = 0; pw1[i] = 0; pdl[i] = 0;
    if (idx < cnt) {
      uint2 p = pairs[e0 + idx];
      pw0[i] = p.x; pw1[i] = p.y;
      pdl[i] = (int)(p.x >> 26);
      atomicAdd(&lfill[pdl[i]], 1);
    }
  }
  __syncthreads();

  // exclusive scan of the 64 counters (wave 0)
  if (tid < 64) {
    int v = lfill[tid];
    int sc = v;
#pragma unroll
    for (int off = 1; off < 64; off <<= 1) {
      int t = __shfl_up(sc, off);
      if (tid >= off) sc += t;
    }
    lstart[tid + 1] = sc;
    if (tid == 0) lstart[0] = 0;
  }
  __syncthreads();
  if (tid < NPB) lfill[tid] = lstart[tid];
  __syncthreads();

  // scatter into dst-sorted LDS order
#pragma unroll
  for (int i = 0; i < 8; ++i) {
    int idx = tid + i * 256;
    if (idx < cnt) {
      int pos = atomicAdd(&lfill[pdl[i]], 1);
      sorted[pos] = make_uint2(pw0[i] & 0x1ffffu, pw1[i]);
    }
  }
  __syncthreads();

  // wave-per-node: gather ftb[src] rows, weight, normalize by gate-sum
  const int lane = tid & 63;
  const int wv = tid >> 6;
  const int g16 = lane >> 4, li = lane & 15;
  for (int j = wv; j < NPB; j += 4) {
    int g = (bkt << NPB_SHIFT) + j;
    if (g >= n) break;
    int s0 = lstart[j], s1 = lstart[j + 1];
    float acc[8] = {0.f, 0.f, 0.f, 0.f, 0.f, 0.f, 0.f, 0.f};
    float wsum = 0.f;
    for (int base = s0; base < s1; base += 64) {
      int c = min(64, s1 - base);
      int sidx = 0;
      float w = 0.f;
      if (lane < c) {
        uint2 p = sorted[base + lane];
        sidx = (int)p.x;
        w = __uint_as_float(p.y);
      }
      wsum += w;
      int nj = (c + 3) >> 2;
      for (int jj = 0; jj < nj; ++jj) {
        int idx = 4 * jj + g16;
        int sj = __shfl(sidx, idx);
        float wj = __shfl(w, idx);   // 0 beyond c
        uint4 v = ((const uint4*)(ftb + (size_t)sj * 128))[li];
        acc[0] += wj * __uint_as_float(v.x << 16);          // elem li*8+0
        acc[1] += wj * __uint_as_float(v.x & 0xffff0000u);  // elem li*8+1
        acc[2] += wj * __uint_as_float(v.y << 16);
        acc[3] += wj * __uint_as_float(v.y & 0xffff0000u);
        acc[4] += wj * __uint_as_float(v.z << 16);
        acc[5] += wj * __uint_as_float(v.z & 0xffff0000u);
        acc[6] += wj * __uint_as_float(v.w << 16);
        acc[7] += wj * __uint_as_float(v.w & 0xffff0000u);
      }
    }
    // z = sum of gates over the node's edges (self-loop => z >= 1)
#pragma unroll
    for (int off = 1; off < 64; off <<= 1) wsum += __shfl_xor(wsum, off);
    float zinv = 1.0f / wsum;
#pragma unroll
    for (int i = 0; i < 8; ++i) {
      acc[i] += __shfl_xor(acc[i], 16);
      acc[i] += __shfl_xor(acc[i], 32);
      acc[i] *= zinv;
    }
    if (lane < 16) {
      float4* op = (float4*)(out + (size_t)g * 128 + li * 8);
      op[0] = make_float4(acc[0], acc[1], acc[2], acc[3]);
      op[1] = make_float4(acc[4], acc[5], acc[6], acc[7]);
    }
  }
}

// ---------------------------------------------------------------------------
extern "C" void kernel_launch(void* const* d_in, const int* in_sizes, int n_in,
                              void* d_out, int out_size, void* d_ws,
                              size_t ws_size, hipStream_t stream) {
  const float* x      = (const float*)d_in[0];
  const float* W      = (const float*)d_in[1];
  const float* b      = (const float*)d_in[2];
  const float* attn_l = (const float*)d_in[3];
  const float* attn_r = (const float*)d_in[4];
  const float* bias   = (const float*)d_in[5];
  const int*   src    = (const int*)d_in[6];
  const int*   dst    = (const int*)d_in[7];

  const int n  = in_sizes[0] / 128;        // 100000
  const int E  = in_sizes[6];              // 1700000
  const int NB = (n + NPB - 1) / NPB;      // 1563 buckets

  // workspace: ftb bf16[n*128] | a1[n] | a2[n] | boff[NB+1] | bcnt[NB*4]
  //            | bfill[NB*4] | (align16) | pairs uint2[E]
  ushort* ftb  = (ushort*)d_ws;
  float*  a1   = (float*)(ftb + (size_t)n * 128);
  float*  a2   = a1 + n;
  int*    boff = (int*)(a2 + n);
  int*    bcnt = boff + (NB + 1);
  int*    bfill = bcnt + (size_t)NB * 4;
  uintptr_t pp = (uintptr_t)(bfill + (size_t)NB * 4);
  pp = (pp + 15u) & ~(uintptr_t)15u;
  uint2*  pairs = (uint2*)pp;

  (void)hipMemsetAsync(bcnt, 0, (size_t)NB * 4 * sizeof(int), stream);

  gemm_ft<<<(n + 63) / 64, 256, 0, stream>>>(x, W, b, attn_l, attn_r, ftb, a1,
                                             a2, n);
  hist_bucket<<<(E + 255) / 256, 256, 0, stream>>>(dst, bcnt, E);
  scan_buckets<<<1, 1024, 0, stream>>>(bcnt, boff, bfill, NB);
  edge_gate_scatter<<<(E + 255) / 256, 256, 0, stream>>>(src, dst, a1, a2, bias,
                                                         bfill, pairs, E);
  aggregate_bucket<<<NB, 256, 0, stream>>>(pairs, boff, ftb, (float*)d_out, n);
}

// Round 12
// 426.942 us; speedup vs baseline: 1.0201x; 1.0201x over previous
//
#include <hip/hip_runtime.h>
#include <hip/hip_bf16.h>

// Hard-concrete constants
#define BETA_INV 1.51515151515f   // 1/0.66
#define ZMG      1.2f             // ZETA - GAMMA
#define GAMMA_C  (-0.1f)

#define NPB        64             // nodes per bucket
#define NPB_SHIFT  6
#define CAP        2048           // max edges per bucket (mean 1088, sigma 32)
#define NTAG       8              // pseudo-XCD tags (blockIdx & 7)

// fp32 -> bf16 (round-to-nearest-even), as raw ushort bits
__device__ __forceinline__ ushort f32_to_bf16(float f) {
  unsigned u = __float_as_uint(f);
  u += 0x7fffu + ((u >> 16) & 1u);
  return (ushort)(u >> 16);
}

// ---------------------------------------------------------------------------
// Kernel 1: ft = x @ W + b (bf16 out), fused a1 = ft.attn_l, a2 = ft.attn_r
// 64 rows x 128 cols per block of 256 threads. x tile in LDS; W from global
// (L2-resident broadcast).
// ---------------------------------------------------------------------------
__global__ __launch_bounds__(256, 3) void gemm_ft(
    const float* __restrict__ x, const float* __restrict__ W,
    const float* __restrict__ bvec, const float* __restrict__ attn_l,
    const float* __restrict__ attn_r, ushort* __restrict__ ftb,
    float* __restrict__ a1, float* __restrict__ a2, int n) {
  __shared__ float xs[64 * 132];
  const int tid = threadIdx.x;

  const int row0 = blockIdx.x * 64;
  for (int i = tid; i < 2048; i += 256) {
    int r = i >> 5, c4 = i & 31;
    int gr = row0 + r;
    float4 v = make_float4(0.f, 0.f, 0.f, 0.f);
    if (gr < n) v = ((const float4*)(x + (size_t)gr * 128))[c4];
    *(float4*)(xs + r * 132 + c4 * 4) = v;
  }
  __syncthreads();

  const int tc = tid & 31;   // col group (4 cols)
  const int tr = tid >> 5;   // row group (8 rows)
  float4 bb = ((const float4*)bvec)[tc];
  float4 acc[8];
#pragma unroll
  for (int r = 0; r < 8; ++r) acc[r] = bb;

  for (int k4 = 0; k4 < 32; ++k4) {
    float4 w0 = ((const float4*)(W + (k4 * 4 + 0) * 128))[tc];
    float4 w1 = ((const float4*)(W + (k4 * 4 + 1) * 128))[tc];
    float4 w2 = ((const float4*)(W + (k4 * 4 + 2) * 128))[tc];
    float4 w3 = ((const float4*)(W + (k4 * 4 + 3) * 128))[tc];
#pragma unroll
    for (int r = 0; r < 8; ++r) {
      float4 xv = *(const float4*)(xs + (8 * tr + r) * 132 + k4 * 4);
      acc[r].x += xv.x * w0.x + xv.y * w1.x + xv.z * w2.x + xv.w * w3.x;
      acc[r].y += xv.x * w0.y + xv.y * w1.y + xv.z * w2.y + xv.w * w3.y;
      acc[r].z += xv.x * w0.z + xv.y * w1.z + xv.z * w2.z + xv.w * w3.z;
      acc[r].w += xv.x * w0.w + xv.y * w1.w + xv.z * w2.w + xv.w * w3.w;
    }
  }

  float4 al = ((const float4*)attn_l)[tc];
  float4 ar = ((const float4*)attn_r)[tc];
#pragma unroll
  for (int r = 0; r < 8; ++r) {
    int gr = row0 + 8 * tr + r;
    if (gr < n) {
      ushort4 h;
      h.x = f32_to_bf16(acc[r].x);
      h.y = f32_to_bf16(acc[r].y);
      h.z = f32_to_bf16(acc[r].z);
      h.w = f32_to_bf16(acc[r].w);
      *(ushort4*)(ftb + (size_t)gr * 128 + tc * 4) = h;
    }
    float s1 = acc[r].x * al.x + acc[r].y * al.y + acc[r].z * al.z +
               acc[r].w * al.w;
    float s2 = acc[r].x * ar.x + acc[r].y * ar.y + acc[r].z * ar.z +
               acc[r].w * ar.w;
#pragma unroll
    for (int off = 16; off; off >>= 1) {
      s1 += __shfl_xor(s1, off);
      s2 += __shfl_xor(s2, off);
    }
    if (tc == 0 && gr < n) {
      a1[gr] = s1;
      a2[gr] = s2;
    }
  }
}

// ---------------------------------------------------------------------------
// Kernel 2: per-(tag, bucket) histogram. tag = blockIdx & 7 approximates the
// XCD; layout [tag][bkt] gives each XCD a private contiguous counter region
// (no cross-XCD line sharing). The e->block mapping here MUST match
// edge_gate_scatter exactly (it does: same grid, e = bid*256+tid).
// ---------------------------------------------------------------------------
__global__ __launch_bounds__(256) void hist_bucket(const int* __restrict__ dst,
                                                   int* __restrict__ bcnt,
                                                   int E, int NB) {
  int bid = blockIdx.x;
  int e = bid * 256 + threadIdx.x;
  if (e < E) {
    int bkt = dst[e] >> NPB_SHIFT;
    atomicAdd(&bcnt[(bid & (NTAG - 1)) * NB + bkt], 1);
  }
}

// ---------------------------------------------------------------------------
// Kernel 3: single-block scan over NB*8 sub-segments in (bkt-major,
// tag-minor) order -> boff[NB*8+1]; bfill[tag*NB+bkt] = sub-segment start.
// Bucket b then occupies [boff[8b], boff[8b+8]) contiguously.
// ---------------------------------------------------------------------------
__global__ __launch_bounds__(1024) void scan_buckets(
    const int* __restrict__ bcnt, int* __restrict__ boff,
    int* __restrict__ bfill, int NB) {
  __shared__ int sd[1024];
  __shared__ int carry_s;
  const int NB8 = NB * NTAG;
  if (threadIdx.x == 0) carry_s = 0;
  int nchunk = (NB8 + 1023) / 1024;
  for (int c = 0; c < nchunk; ++c) {
    int i = c * 1024 + threadIdx.x;
    int bkt = i >> 3, tag = i & 7;
    int v = (i < NB8) ? bcnt[tag * NB + bkt] : 0;
    __syncthreads();
    sd[threadIdx.x] = v;
    __syncthreads();
    for (int off = 1; off < 1024; off <<= 1) {
      int t = (threadIdx.x >= off) ? sd[threadIdx.x - off] : 0;
      __syncthreads();
      sd[threadIdx.x] += t;
      __syncthreads();
    }
    int carry = carry_s;
    if (i < NB8) {
      int excl = carry + sd[threadIdx.x] - v;
      boff[i] = excl;
      bfill[tag * NB + bkt] = excl;
    }
    __syncthreads();
    if (threadIdx.x == 1023) carry_s = carry + sd[1023];
  }
  __syncthreads();
  if (threadIdx.x == 0) boff[NB8] = carry_s;
}

// ---------------------------------------------------------------------------
// Kernel 4: gate + scatter uint2{(dst_local<<26)|src, gate_bits} into the
// (tag, bucket) sub-segment. Same-tag claimers share an L2 (tag ~ XCD), so
// consecutive 8B writes merge into full lines that fit in that L2.
// ---------------------------------------------------------------------------
__global__ __launch_bounds__(256) void edge_gate_scatter(
    const int* __restrict__ src, const int* __restrict__ dst,
    const float* __restrict__ a1, const float* __restrict__ a2,
    const float* __restrict__ bias, int* __restrict__ bfill,
    uint2* __restrict__ pairs, int E, int NB) {
  int bid = blockIdx.x;
  int e = bid * 256 + threadIdx.x;
  if (e >= E) return;
  int s = src[e], d = dst[e];
  float val = 1.0f;
  if (s != d) {
    float logit = (a1[s] + a2[d] + bias[0]) * BETA_INV;
    float sg = 1.0f / (1.0f + __expf(-logit));
    val = fminf(fmaxf(sg * ZMG + GAMMA_C, 0.0f), 1.0f);
  }
  int bkt = d >> NPB_SHIFT;
  unsigned dl = (unsigned)(d & (NPB - 1));
  int pos = atomicAdd(&bfill[(bid & (NTAG - 1)) * NB + bkt], 1);
  pairs[pos] = make_uint2((dl << 26) | (unsigned)s, __float_as_uint(val));
}

// ---------------------------------------------------------------------------
// Kernel 5: per-bucket aggregate. Block = one bucket: LDS counting-sort the
// bucket's edges by local dst, then wave-per-node gather+accumulate.
// ---------------------------------------------------------------------------
__global__ __launch_bounds__(256) void aggregate_bucket(
    const uint2* __restrict__ pairs, const int* __restrict__ boff,
    const ushort* __restrict__ ftb, float* __restrict__ out, int n) {
  __shared__ uint2 sorted[CAP];
  __shared__ int lstart[NPB + 1];
  __shared__ int lfill[NPB];
  const int tid = threadIdx.x;
  const int bkt = blockIdx.x;
  const int e0 = boff[bkt * NTAG];
  const int cnt = min(boff[bkt * NTAG + NTAG] - e0, CAP);

  if (tid < NPB) lfill[tid] = 0;
  __syncthreads();

  // load this bucket's edges into registers (static indexing), count per dl
  unsigned pw0[8], pw1[8];
  int pdl[8];
#pragma unroll
  for (int i = 0; i < 8; ++i) {
    int idx = tid + i * 256;
    pw0[i] = 0; pw1[i] = 0; pdl[i] = 0;
    if (idx < cnt) {
      uint2 p = pairs[e0 + idx];
      pw0[i] = p.x; pw1[i] = p.y;
      pdl[i] = (int)(p.x >> 26);
      atomicAdd(&lfill[pdl[i]], 1);
    }
  }
  __syncthreads();

  // exclusive scan of the 64 counters (wave 0)
  if (tid < 64) {
    int v = lfill[tid];
    int sc = v;
#pragma unroll
    for (int off = 1; off < 64; off <<= 1) {
      int t = __shfl_up(sc, off);
      if (tid >= off) sc += t;
    }
    lstart[tid + 1] = sc;
    if (tid == 0) lstart[0] = 0;
  }
  __syncthreads();
  if (tid < NPB) lfill[tid] = lstart[tid];
  __syncthreads();

  // scatter into dst-sorted LDS order
#pragma unroll
  for (int i = 0; i < 8; ++i) {
    int idx = tid + i * 256;
    if (idx < cnt) {
      int pos = atomicAdd(&lfill[pdl[i]], 1);
      sorted[pos] = make_uint2(pw0[i] & 0x1ffffu, pw1[i]);
    }
  }
  __syncthreads();

  // wave-per-node: gather ftb[src] rows, weight, normalize by gate-sum
  const int lane = tid & 63;
  const int wv = tid >> 6;
  const int g16 = lane >> 4, li = lane & 15;
  for (int j = wv; j < NPB; j += 4) {
    int g = (bkt << NPB_SHIFT) + j;
    if (g >= n) break;
    int s0 = lstart[j], s1 = lstart[j + 1];
    float acc[8] = {0.f, 0.f, 0.f, 0.f, 0.f, 0.f, 0.f, 0.f};
    float wsum = 0.f;
    for (int base = s0; base < s1; base += 64) {
      int c = min(64, s1 - base);
      int sidx = 0;
      float w = 0.f;
      if (lane < c) {
        uint2 p = sorted[base + lane];
        sidx = (int)p.x;
        w = __uint_as_float(p.y);
      }
      wsum += w;
      int nj = (c + 3) >> 2;
      for (int jj = 0; jj < nj; ++jj) {
        int idx = 4 * jj + g16;
        int sj = __shfl(sidx, idx);
        float wj = __shfl(w, idx);   // 0 beyond c (and for zero-gate edges)
        if (wj != 0.f) {
          uint4 v = ((const uint4*)(ftb + (size_t)sj * 128))[li];
          acc[0] += wj * __uint_as_float(v.x << 16);          // elem li*8+0
          acc[1] += wj * __uint_as_float(v.x & 0xffff0000u);  // elem li*8+1
          acc[2] += wj * __uint_as_float(v.y << 16);
          acc[3] += wj * __uint_as_float(v.y & 0xffff0000u);
          acc[4] += wj * __uint_as_float(v.z << 16);
          acc[5] += wj * __uint_as_float(v.z & 0xffff0000u);
          acc[6] += wj * __uint_as_float(v.w << 16);
          acc[7] += wj * __uint_as_float(v.w & 0xffff0000u);
        }
      }
    }
    // z = sum of gates over the node's edges (self-loop => z >= 1)
#pragma unroll
    for (int off = 1; off < 64; off <<= 1) wsum += __shfl_xor(wsum, off);
    float zinv = 1.0f / wsum;
#pragma unroll
    for (int i = 0; i < 8; ++i) {
      acc[i] += __shfl_xor(acc[i], 16);
      acc[i] += __shfl_xor(acc[i], 32);
      acc[i] *= zinv;
    }
    if (lane < 16) {
      float4* op = (float4*)(out + (size_t)g * 128 + li * 8);
      op[0] = make_float4(acc[0], acc[1], acc[2], acc[3]);
      op[1] = make_float4(acc[4], acc[5], acc[6], acc[7]);
    }
  }
}

// ---------------------------------------------------------------------------
extern "C" void kernel_launch(void* const* d_in, const int* in_sizes, int n_in,
                              void* d_out, int out_size, void* d_ws,
                              size_t ws_size, hipStream_t stream) {
  const float* x      = (const float*)d_in[0];
  const float* W      = (const float*)d_in[1];
  const float* b      = (const float*)d_in[2];
  const float* attn_l = (const float*)d_in[3];
  const float* attn_r = (const float*)d_in[4];
  const float* bias   = (const float*)d_in[5];
  const int*   src    = (const int*)d_in[6];
  const int*   dst    = (const int*)d_in[7];

  const int n   = in_sizes[0] / 128;        // 100000
  const int E   = in_sizes[6];              // 1700000
  const int NB  = (n + NPB - 1) / NPB;      // 1563 buckets
  const int NB8 = NB * NTAG;

  // workspace: ftb bf16[n*128] | a1[n] | a2[n] | boff[NB8+1] | bcnt[NB8]
  //            | bfill[NB8] | (align16) | pairs uint2[E]
  ushort* ftb   = (ushort*)d_ws;
  float*  a1    = (float*)(ftb + (size_t)n * 128);
  float*  a2    = a1 + n;
  int*    boff  = (int*)(a2 + n);
  int*    bcnt  = boff + (NB8 + 1);
  int*    bfill = bcnt + NB8;
  uintptr_t pp  = (uintptr_t)(bfill + NB8);
  pp = (pp + 15u) & ~(uintptr_t)15u;
  uint2*  pairs = (uint2*)pp;

  (void)hipMemsetAsync(bcnt, 0, (size_t)NB8 * sizeof(int), stream);

  gemm_ft<<<(n + 63) / 64, 256, 0, stream>>>(x, W, b, attn_l, attn_r, ftb, a1,
                                             a2, n);
  hist_bucket<<<(E + 255) / 256, 256, 0, stream>>>(dst, bcnt, E, NB);
  scan_buckets<<<1, 1024, 0, stream>>>(bcnt, boff, bfill, NB);
  edge_gate_scatter<<<(E + 255) / 256, 256, 0, stream>>>(src, dst, a1, a2, bias,
                                                         bfill, pairs, E, NB);
  aggregate_bucket<<<NB, 256, 0, stream>>>(pairs, boff, ftb, (float*)d_out, n);
}